// Round 1
// baseline (86.836 us; speedup 1.0000x reference)
//
#include <hip/hip_runtime.h>
#include <math.h>

#define EPS2f 0.25f
#define EPS4f 0.0625f
#define BB 4

// ---------------------------------------------------------------------------
// Kernel 1: precompute per-(ij,k) tables.
//   AB_T[k*1024 + ij] = { A = 1/Sigma, B2 = 2*mu_t/Sigma }   (transposed: phase-A coalesced)
//   KV  [ij*64  + k ] = { K, Vm = v - K*mu_t }               (phase-B coalesced)
//   C0  [ij]          = sum_k ( mu_t^2/Sigma + log(Sigma) )
// grid 1024 (one block per ij), block 64 (one thread per k) = 1 wave.
// ---------------------------------------------------------------------------
__global__ __launch_bounds__(64) void precomp_kernel(
    const float* __restrict__ Mu0, const float* __restrict__ Mu1,
    const float* __restrict__ S0,  const float* __restrict__ S1,
    const float* __restrict__ tptr,
    float2* __restrict__ AB_T, float2* __restrict__ KV,
    float* __restrict__ C0)
{
    const int ij = blockIdx.x;
    const int k  = threadIdx.x;           // 0..63
    const int i  = ij >> 5;               // N0=32
    const int j  = ij & 31;               // N1=32
    const float t   = *tptr;
    const float omt = 1.0f - t;

    const float s0 = S0[i * 64 + k];
    const float s1 = S1[j * 64 + k];
    const float m0 = Mu0[i * 64 + k];
    const float m1 = Mu1[j * 64 + k];

    const float ds  = sqrtf(4.0f * s0 * s1 + EPS4f);
    const float cs  = 0.5f * (ds - EPS2f);
    const float mt  = omt * m0 + t * m1;
    const float sig = omt * omt * s0 + t * t * s1
                    + 2.0f * t * omt * (cs + 0.5f * EPS2f);
    const float isig = 1.0f / sig;
    // St = t*S1 + (1-t)*Cs - ((1-t)*S0 + t*Cs) - eps2*t
    const float st = t * s1 - omt * s0 + (omt - t) * cs - EPS2f * t;
    const float kk = st * isig;
    const float v  = m1 - m0;

    AB_T[(k << 10) + ij] = make_float2(isig, 2.0f * mt * isig);
    KV[(ij << 6) + k]    = make_float2(kk, v - kk * mt);

    float c = mt * mt * isig + __logf(sig);
    #pragma unroll
    for (int off = 32; off >= 1; off >>= 1)
        c += __shfl_xor(c, off, 64);
    if (k == 0) C0[ij] = c;
}

// ---------------------------------------------------------------------------
// Kernel 2: main. One block = BB=4 batch rows. 512 threads = 8 waves.
// Phase A: thread handles ij = tid and tid+512; quad via expanded FMA stream;
//          W[ij] (float4 over bb) -> LDS; per-bb den partial -> wave reduce.
// Phase B: lane = k, wave w handles ij in [w*128, w*128+128);
//          num[bb] += W * (K*x + Vm); combine 8 waves via LDS.
// ---------------------------------------------------------------------------
__global__ __launch_bounds__(512) void gmm_main_kernel(
    const float* __restrict__ X,   const float* __restrict__ Lam,
    const float* __restrict__ C0,
    const float2* __restrict__ AB_T, const float2* __restrict__ KV,
    float* __restrict__ out)
{
    __shared__ float4 XsT[64];        // [k] = x for bb=0..3
    __shared__ float4 Wl[1024];       // [ij] = W for bb=0..3
    __shared__ float  denp[8 * BB];   // per-wave per-bb den partials
    __shared__ float  red[8 * 64 * BB]; // [w][k][bb] num partials

    const int tid  = threadIdx.x;
    const int lane = tid & 63;
    const int w    = tid >> 6;        // 0..7
    const int b0   = blockIdx.x * BB;

    if (tid < 64 * BB) {
        // X[b0*64 + tid]: bb = tid>>6, k = tid&63  -> XsT[k].component[bb]
        ((float*)XsT)[(tid & 63) * BB + (tid >> 6)] = X[b0 * 64 + tid];
    }
    __syncthreads();

    // ---- Phase A ----
    const int ij0 = tid;
    const int ij1 = tid + 512;
    float q0a = 0.f, q0b = 0.f, q0c = 0.f, q0d = 0.f;
    float q1a = 0.f, q1b = 0.f, q1c = 0.f, q1d = 0.f;
    #pragma unroll 4
    for (int k = 0; k < 64; ++k) {
        const float2 ab0 = AB_T[(k << 10) + ij0];
        const float2 ab1 = AB_T[(k << 10) + ij1];
        const float4 xk  = XsT[k];
        q0a = fmaf(fmaf(ab0.x, xk.x, -ab0.y), xk.x, q0a);
        q0b = fmaf(fmaf(ab0.x, xk.y, -ab0.y), xk.y, q0b);
        q0c = fmaf(fmaf(ab0.x, xk.z, -ab0.y), xk.z, q0c);
        q0d = fmaf(fmaf(ab0.x, xk.w, -ab0.y), xk.w, q0d);
        q1a = fmaf(fmaf(ab1.x, xk.x, -ab1.y), xk.x, q1a);
        q1b = fmaf(fmaf(ab1.x, xk.y, -ab1.y), xk.y, q1b);
        q1c = fmaf(fmaf(ab1.x, xk.z, -ab1.y), xk.z, q1c);
        q1d = fmaf(fmaf(ab1.x, xk.w, -ab1.y), xk.w, q1d);
    }

    const float c00 = C0[ij0], l0 = Lam[ij0];
    const float c01 = C0[ij1], l1 = Lam[ij1];
    #define WCALC(q, c, l) (__expf(fminf(fmaxf(-0.5f * ((q) + (c)), -50.0f), 50.0f)) * (l))
    float4 w0, w1;
    w0.x = WCALC(q0a, c00, l0); w0.y = WCALC(q0b, c00, l0);
    w0.z = WCALC(q0c, c00, l0); w0.w = WCALC(q0d, c00, l0);
    w1.x = WCALC(q1a, c01, l1); w1.y = WCALC(q1b, c01, l1);
    w1.z = WCALC(q1c, c01, l1); w1.w = WCALC(q1d, c01, l1);
    #undef WCALC
    Wl[ij0] = w0;
    Wl[ij1] = w1;

    // per-bb den partials: reduce across the wave
    float d0 = w0.x + w1.x;
    float d1 = w0.y + w1.y;
    float d2 = w0.z + w1.z;
    float d3 = w0.w + w1.w;
    #pragma unroll
    for (int off = 32; off >= 1; off >>= 1) {
        d0 += __shfl_xor(d0, off, 64);
        d1 += __shfl_xor(d1, off, 64);
        d2 += __shfl_xor(d2, off, 64);
        d3 += __shfl_xor(d3, off, 64);
    }
    if (lane == 0) {
        denp[w * BB + 0] = d0;
        denp[w * BB + 1] = d1;
        denp[w * BB + 2] = d2;
        denp[w * BB + 3] = d3;
    }
    __syncthreads();

    // ---- Phase B ----
    const float4 xk4 = XsT[lane];     // x[bb] at k = lane
    float n0 = 0.f, n1 = 0.f, n2 = 0.f, n3 = 0.f;
    const int ijbase = w * 128;
    #pragma unroll 4
    for (int c = 0; c < 128; ++c) {
        const int ij = ijbase + c;
        const float4 wv = Wl[ij];                 // LDS broadcast
        const float2 kv = KV[(ij << 6) + lane];   // coalesced
        float u;
        u = fmaf(kv.x, xk4.x, kv.y); n0 = fmaf(wv.x, u, n0);
        u = fmaf(kv.x, xk4.y, kv.y); n1 = fmaf(wv.y, u, n1);
        u = fmaf(kv.x, xk4.z, kv.y); n2 = fmaf(wv.z, u, n2);
        u = fmaf(kv.x, xk4.w, kv.y); n3 = fmaf(wv.w, u, n3);
    }
    {
        float* r = &red[(w * 64 + lane) * BB];
        r[0] = n0; r[1] = n1; r[2] = n2; r[3] = n3;
    }
    __syncthreads();

    // ---- Epilogue: combine 8 waves, divide, store ----
    if (tid < 256) {
        const int bb = tid >> 6;    // wave-uniform
        const int k  = tid & 63;
        float s = 0.f, d = 0.f;
        #pragma unroll
        for (int ww = 0; ww < 8; ++ww) {
            s += red[(ww * 64 + k) * BB + bb];
            d += denp[ww * BB + bb];
        }
        out[b0 * 64 + tid] = s / d;
    }
}

extern "C" void kernel_launch(void* const* d_in, const int* in_sizes, int n_in,
                              void* d_out, int out_size, void* d_ws, size_t ws_size,
                              hipStream_t stream) {
    const float* X   = (const float*)d_in[0];
    const float* Mu0 = (const float*)d_in[1];
    const float* Mu1 = (const float*)d_in[2];
    const float* S0  = (const float*)d_in[3];
    const float* S1  = (const float*)d_in[4];
    const float* Lam = (const float*)d_in[5];
    const float* t   = (const float*)d_in[6];
    float* out = (float*)d_out;

    char* ws = (char*)d_ws;
    float2* AB_T = (float2*)(ws);                 // 65536 * 8B = 512 KiB
    float2* KV   = (float2*)(ws + (512 << 10));   // 512 KiB
    float*  C0   = (float*)(ws + (1024 << 10));   // 4 KiB

    precomp_kernel<<<1024, 64, 0, stream>>>(Mu0, Mu1, S0, S1, t, AB_T, KV, C0);
    gmm_main_kernel<<<256, 512, 0, stream>>>(X, Lam, C0, AB_T, KV, out);
}

// Round 2
// 84.802 us; speedup vs baseline: 1.0240x; 1.0240x over previous
//
#include <hip/hip_runtime.h>
#include <math.h>

#define EPS2f 0.25f
#define EPS4f 0.0625f
#define BB 4

// ---------------------------------------------------------------------------
// Kernel 1: precompute per-(ij,k) tables.
//   AB_T[k*1024 + ij] = { A = 1/Sigma, B2 = 2*mu_t/Sigma }   (phase-A coalesced)
//   KV  [ij*64  + k ] = { K, Vm = v - K*mu_t }               (phase-B coalesced)
//   C0  [ij]          = sum_k ( mu_t^2/Sigma + log(Sigma) )
// ---------------------------------------------------------------------------
__global__ __launch_bounds__(64) void precomp_kernel(
    const float* __restrict__ Mu0, const float* __restrict__ Mu1,
    const float* __restrict__ S0,  const float* __restrict__ S1,
    const float* __restrict__ tptr,
    float2* __restrict__ AB_T, float2* __restrict__ KV,
    float* __restrict__ C0)
{
    const int ij = blockIdx.x;
    const int k  = threadIdx.x;           // 0..63
    const int i  = ij >> 5;               // N0=32
    const int j  = ij & 31;               // N1=32
    const float t   = *tptr;
    const float omt = 1.0f - t;

    const float s0 = S0[i * 64 + k];
    const float s1 = S1[j * 64 + k];
    const float m0 = Mu0[i * 64 + k];
    const float m1 = Mu1[j * 64 + k];

    const float ds  = sqrtf(4.0f * s0 * s1 + EPS4f);
    const float cs  = 0.5f * (ds - EPS2f);
    const float mt  = omt * m0 + t * m1;
    const float sig = omt * omt * s0 + t * t * s1
                    + 2.0f * t * omt * (cs + 0.5f * EPS2f);
    const float isig = 1.0f / sig;
    const float st = t * s1 - omt * s0 + (omt - t) * cs - EPS2f * t;
    const float kk = st * isig;
    const float v  = m1 - m0;

    AB_T[(k << 10) + ij] = make_float2(isig, 2.0f * mt * isig);
    KV[(ij << 6) + k]    = make_float2(kk, v - kk * mt);

    float c = mt * mt * isig + __logf(sig);
    #pragma unroll
    for (int off = 32; off >= 1; off >>= 1)
        c += __shfl_xor(c, off, 64);
    if (k == 0) C0[ij] = c;
}

// ---------------------------------------------------------------------------
// Kernel 2: main. One block = BB=4 batch rows. 1024 threads = 16 waves
// (4 waves/SIMD — double round-1's occupancy, key for hiding L2 latency).
// Phase A: thread tid owns ij = tid (one ij each); W -> LDS.
// Phase B: wave w owns ij in [w*64, w*64+64) — exactly the ij range its own
//          lanes produced in phase A, so NO barrier needed between A and B.
// ---------------------------------------------------------------------------
__global__ __launch_bounds__(1024, 4) void gmm_main_kernel(
    const float* __restrict__ X,   const float* __restrict__ Lam,
    const float* __restrict__ C0,
    const float2* __restrict__ AB_T, const float2* __restrict__ KV,
    float* __restrict__ out)
{
    __shared__ float4 XsT[64];           // [k] = x for bb=0..3
    __shared__ float4 Wl[1024];          // [ij] = W for bb=0..3
    __shared__ float  denp[16 * BB];     // per-wave per-bb den partials
    __shared__ float  red[16 * 64 * 5];  // [w][k][bb], stride 5 = no bank conflict

    const int tid  = threadIdx.x;
    const int lane = tid & 63;
    const int w    = tid >> 6;           // 0..15
    const int b0   = blockIdx.x * BB;

    if (tid < 64 * BB) {
        // X[b0*64 + tid]: bb = tid>>6, k = tid&63  -> XsT[k].component[bb]
        ((float*)XsT)[(tid & 63) * BB + (tid >> 6)] = X[b0 * 64 + tid];
    }
    __syncthreads();

    // ---- Phase A: one ij per thread ----
    const int ij = tid;
    float qa = 0.f, qb = 0.f, qc = 0.f, qd = 0.f;
    #pragma unroll 8
    for (int k = 0; k < 64; ++k) {
        const float2 ab = AB_T[(k << 10) + ij];
        const float4 xk = XsT[k];
        qa = fmaf(fmaf(ab.x, xk.x, -ab.y), xk.x, qa);
        qb = fmaf(fmaf(ab.x, xk.y, -ab.y), xk.y, qb);
        qc = fmaf(fmaf(ab.x, xk.z, -ab.y), xk.z, qc);
        qd = fmaf(fmaf(ab.x, xk.w, -ab.y), xk.w, qd);
    }

    const float c0 = C0[ij], l0 = Lam[ij];
    #define WCALC(q) (__expf(fminf(fmaxf(-0.5f * ((q) + c0), -50.0f), 50.0f)) * l0)
    float4 wv4;
    wv4.x = WCALC(qa); wv4.y = WCALC(qb); wv4.z = WCALC(qc); wv4.w = WCALC(qd);
    #undef WCALC
    Wl[ij] = wv4;

    // per-bb den partials across the wave
    float d0 = wv4.x, d1 = wv4.y, d2 = wv4.z, d3 = wv4.w;
    #pragma unroll
    for (int off = 32; off >= 1; off >>= 1) {
        d0 += __shfl_xor(d0, off, 64);
        d1 += __shfl_xor(d1, off, 64);
        d2 += __shfl_xor(d2, off, 64);
        d3 += __shfl_xor(d3, off, 64);
    }
    if (lane == 0) {
        denp[w * BB + 0] = d0;
        denp[w * BB + 1] = d1;
        denp[w * BB + 2] = d2;
        denp[w * BB + 3] = d3;
    }

    // ---- Phase B: wave w consumes ij range its own lanes produced ----
    // (same-wave LDS write->read: hardware lgkmcnt ordering suffices, no
    //  __syncthreads needed — cross-wave data (denp/red) is fenced below.)
    const float4 xk4 = XsT[lane];        // x[bb] at k = lane
    float n0 = 0.f, n1 = 0.f, n2 = 0.f, n3 = 0.f;
    const int ijbase = w * 64;
    #pragma unroll 8
    for (int c = 0; c < 64; ++c) {
        const int ijb = ijbase + c;
        const float4 wv = Wl[ijb];                 // LDS broadcast (own wave's data)
        const float2 kv = KV[(ijb << 6) + lane];   // coalesced 512B/wave
        float u;
        u = fmaf(kv.x, xk4.x, kv.y); n0 = fmaf(wv.x, u, n0);
        u = fmaf(kv.x, xk4.y, kv.y); n1 = fmaf(wv.y, u, n1);
        u = fmaf(kv.x, xk4.z, kv.y); n2 = fmaf(wv.z, u, n2);
        u = fmaf(kv.x, xk4.w, kv.y); n3 = fmaf(wv.w, u, n3);
    }
    {
        float* r = &red[(w * 64 + lane) * 5];
        r[0] = n0; r[1] = n1; r[2] = n2; r[3] = n3;
    }
    __syncthreads();

    // ---- Epilogue: combine 16 waves, divide, store ----
    if (tid < 256) {
        const int bb = tid >> 6;    // wave-uniform
        const int k  = tid & 63;
        float s = 0.f, d = 0.f;
        #pragma unroll
        for (int ww = 0; ww < 16; ++ww) {
            s += red[(ww * 64 + k) * 5 + bb];
            d += denp[ww * BB + bb];
        }
        out[b0 * 64 + tid] = s / d;
    }
}

extern "C" void kernel_launch(void* const* d_in, const int* in_sizes, int n_in,
                              void* d_out, int out_size, void* d_ws, size_t ws_size,
                              hipStream_t stream) {
    const float* X   = (const float*)d_in[0];
    const float* Mu0 = (const float*)d_in[1];
    const float* Mu1 = (const float*)d_in[2];
    const float* S0  = (const float*)d_in[3];
    const float* S1  = (const float*)d_in[4];
    const float* Lam = (const float*)d_in[5];
    const float* t   = (const float*)d_in[6];
    float* out = (float*)d_out;

    char* ws = (char*)d_ws;
    float2* AB_T = (float2*)(ws);                 // 512 KiB
    float2* KV   = (float2*)(ws + (512 << 10));   // 512 KiB
    float*  C0   = (float*)(ws + (1024 << 10));   // 4 KiB

    precomp_kernel<<<1024, 64, 0, stream>>>(Mu0, Mu1, S0, S1, t, AB_T, KV, C0);
    gmm_main_kernel<<<256, 1024, 0, stream>>>(X, Lam, C0, AB_T, KV, out);
}

// Round 3
// 80.874 us; speedup vs baseline: 1.0737x; 1.0486x over previous
//
#include <hip/hip_runtime.h>
#include <math.h>

#define EPS2f 0.25f
#define EPS4f 0.0625f
#define BB 4

// ---------------------------------------------------------------------------
// Kernel 1: precompute per-(ij,k) tables.  256 blocks x 256 threads (4 ij/blk).
//   AB4[k2*1024 + ij] = float4{ A(2k2), B2(2k2), A(2k2+1), B2(2k2+1) }
//       where A = 1/Sigma, B2 = 2*mu_t/Sigma     (phase-A: one dwordx4/iter)
//   KV [ij*64 + k]    = float2{ K, Vm = v - K*mu_t }  (phase-B coalesced)
//   C0 [ij]           = sum_k ( mu_t^2/Sigma + log(Sigma) )
// ---------------------------------------------------------------------------
__global__ __launch_bounds__(256) void precomp_kernel(
    const float* __restrict__ Mu0, const float* __restrict__ Mu1,
    const float* __restrict__ S0,  const float* __restrict__ S1,
    const float* __restrict__ tptr,
    float2* __restrict__ AB4, float2* __restrict__ KV,
    float* __restrict__ C0)
{
    const int tid = threadIdx.x;
    const int k   = tid & 63;
    const int ij  = (blockIdx.x << 2) + (tid >> 6);
    const int i   = ij >> 5;              // N0=32
    const int j   = ij & 31;              // N1=32
    const float t   = *tptr;
    const float omt = 1.0f - t;

    const float s0 = S0[i * 64 + k];
    const float s1 = S1[j * 64 + k];
    const float m0 = Mu0[i * 64 + k];
    const float m1 = Mu1[j * 64 + k];

    const float ds  = sqrtf(4.0f * s0 * s1 + EPS4f);
    const float cs  = 0.5f * (ds - EPS2f);
    const float mt  = omt * m0 + t * m1;
    const float sig = omt * omt * s0 + t * t * s1
                    + 2.0f * t * omt * (cs + 0.5f * EPS2f);
    const float isig = 1.0f / sig;
    const float st = t * s1 - omt * s0 + (omt - t) * cs - EPS2f * t;
    const float kk = st * isig;
    const float v  = m1 - m0;

    // float2 element index inside the float4-packed [k2][ij] table:
    //   (k2*1024 + ij)*2 + (k&1)
    AB4[((k >> 1) << 11) + (ij << 1) + (k & 1)] = make_float2(isig, 2.0f * mt * isig);
    KV[(ij << 6) + k] = make_float2(kk, v - kk * mt);

    float c = mt * mt * isig + __logf(sig);
    #pragma unroll
    for (int off = 32; off >= 1; off >>= 1)
        c += __shfl_xor(c, off, 64);
    if (k == 0) C0[ij] = c;
}

// ---------------------------------------------------------------------------
// Kernel 2: main. One block = BB=4 batch rows, 1024 threads = 16 waves.
// Phase A: thread tid owns ij = tid; 32 iters of one dwordx4 table load.
// Phase B: wave w owns ij in [w*64, w*64+64) — same range its lanes produced,
//          so no barrier between A and B.
// ---------------------------------------------------------------------------
__global__ __launch_bounds__(1024, 4) void gmm_main_kernel(
    const float* __restrict__ X,   const float* __restrict__ Lam,
    const float* __restrict__ C0,
    const float4* __restrict__ AB4, const float2* __restrict__ KV,
    float* __restrict__ out)
{
    __shared__ float4 XsT[64];           // [k] = x for bb=0..3
    __shared__ float4 Wl[1024];          // [ij] = W for bb=0..3
    __shared__ float  denp[16 * BB];     // per-wave per-bb den partials
    __shared__ float  red[16 * 64 * 5];  // [w][k][bb], stride 5: no bank conflict

    const int tid  = threadIdx.x;
    const int lane = tid & 63;
    const int w    = tid >> 6;           // 0..15
    const int b0   = blockIdx.x * BB;

    if (tid < 64 * BB) {
        ((float*)XsT)[(tid & 63) * BB + (tid >> 6)] = X[b0 * 64 + tid];
    }
    __syncthreads();

    // ---- Phase A: one ij per thread, k in pairs ----
    const int ij = tid;
    float qa = 0.f, qb = 0.f, qc = 0.f, qd = 0.f;
    #pragma unroll 4
    for (int k2 = 0; k2 < 32; ++k2) {
        const float4 ab = AB4[(k2 << 10) + ij];   // {A0,B0,A1,B1}
        const float4 x0 = XsT[2 * k2];
        const float4 x1 = XsT[2 * k2 + 1];
        qa = fmaf(fmaf(ab.x, x0.x, -ab.y), x0.x, qa);
        qb = fmaf(fmaf(ab.x, x0.y, -ab.y), x0.y, qb);
        qc = fmaf(fmaf(ab.x, x0.z, -ab.y), x0.z, qc);
        qd = fmaf(fmaf(ab.x, x0.w, -ab.y), x0.w, qd);
        qa = fmaf(fmaf(ab.z, x1.x, -ab.w), x1.x, qa);
        qb = fmaf(fmaf(ab.z, x1.y, -ab.w), x1.y, qb);
        qc = fmaf(fmaf(ab.z, x1.z, -ab.w), x1.z, qc);
        qd = fmaf(fmaf(ab.z, x1.w, -ab.w), x1.w, qd);
    }

    const float c0 = C0[ij], l0 = Lam[ij];
    #define WCALC(q) (__expf(fminf(fmaxf(-0.5f * ((q) + c0), -50.0f), 50.0f)) * l0)
    float4 wv4;
    wv4.x = WCALC(qa); wv4.y = WCALC(qb); wv4.z = WCALC(qc); wv4.w = WCALC(qd);
    #undef WCALC
    Wl[ij] = wv4;

    float d0 = wv4.x, d1 = wv4.y, d2 = wv4.z, d3 = wv4.w;
    #pragma unroll
    for (int off = 32; off >= 1; off >>= 1) {
        d0 += __shfl_xor(d0, off, 64);
        d1 += __shfl_xor(d1, off, 64);
        d2 += __shfl_xor(d2, off, 64);
        d3 += __shfl_xor(d3, off, 64);
    }
    if (lane == 0) {
        denp[w * BB + 0] = d0;
        denp[w * BB + 1] = d1;
        denp[w * BB + 2] = d2;
        denp[w * BB + 3] = d3;
    }

    // ---- Phase B: wave w consumes the ij range its own lanes produced ----
    const float4 xk4 = XsT[lane];        // x[bb] at k = lane
    float n0 = 0.f, n1 = 0.f, n2 = 0.f, n3 = 0.f;
    const int ijbase = w * 64;
    #pragma unroll 8
    for (int c = 0; c < 64; ++c) {
        const int ijb = ijbase + c;
        const float4 wv = Wl[ijb];                 // LDS broadcast (own wave's data)
        const float2 kv = KV[(ijb << 6) + lane];   // coalesced 512B/wave
        float u;
        u = fmaf(kv.x, xk4.x, kv.y); n0 = fmaf(wv.x, u, n0);
        u = fmaf(kv.x, xk4.y, kv.y); n1 = fmaf(wv.y, u, n1);
        u = fmaf(kv.x, xk4.z, kv.y); n2 = fmaf(wv.z, u, n2);
        u = fmaf(kv.x, xk4.w, kv.y); n3 = fmaf(wv.w, u, n3);
    }
    {
        float* r = &red[(w * 64 + lane) * 5];
        r[0] = n0; r[1] = n1; r[2] = n2; r[3] = n3;
    }
    __syncthreads();

    // ---- Epilogue: combine 16 waves, divide, store ----
    if (tid < 256) {
        const int bb = tid >> 6;    // wave-uniform
        const int k  = tid & 63;
        float s = 0.f, d = 0.f;
        #pragma unroll
        for (int ww = 0; ww < 16; ++ww) {
            s += red[(ww * 64 + k) * 5 + bb];
            d += denp[ww * BB + bb];
        }
        out[b0 * 64 + tid] = s / d;
    }
}

extern "C" void kernel_launch(void* const* d_in, const int* in_sizes, int n_in,
                              void* d_out, int out_size, void* d_ws, size_t ws_size,
                              hipStream_t stream) {
    const float* X   = (const float*)d_in[0];
    const float* Mu0 = (const float*)d_in[1];
    const float* Mu1 = (const float*)d_in[2];
    const float* S0  = (const float*)d_in[3];
    const float* S1  = (const float*)d_in[4];
    const float* Lam = (const float*)d_in[5];
    const float* t   = (const float*)d_in[6];
    float* out = (float*)d_out;

    char* ws = (char*)d_ws;
    float2* AB4 = (float2*)(ws);                  // 512 KiB (float4-packed view)
    float2* KV  = (float2*)(ws + (512 << 10));    // 512 KiB
    float*  C0  = (float*)(ws + (1024 << 10));    // 4 KiB

    precomp_kernel<<<256, 256, 0, stream>>>(Mu0, Mu1, S0, S1, t, AB4, KV, C0);
    gmm_main_kernel<<<256, 1024, 0, stream>>>(X, Lam, C0, (const float4*)AB4, KV, out);
}